// Round 1
// baseline (53.747 us; speedup 1.0000x reference)
//
#include <hip/hip_runtime.h>

// CenterNeighAtt on MI355X.
// E=512 entities, F=256 features, R=4 relations.
//
// Math notes (exact, not approximations):
//  * alpha = softmax_j(sum_i scores[i,j]) is uniform 1/E because
//    sum_i attention[i,j,f] == 1 (softmax axis=0), so the column sums of
//    scores are a constant (sum_f w_f + E*b) independent of j.
//  * Softmax without max-subtraction: logits bounded by ~20 (h ~ N(0,1),
//    s in [0,1]); exp stays far below f32 overflow, result identical.

#define EE 512
#define FF 256
#define RRR 4

// --- Kernel A: s[i,j] = softmax over j of sum_r adj[r,i,j] -----------------
__global__ __launch_bounds__(256) void kA(const float* __restrict__ adj,
                                          float* __restrict__ s) {
    const int i = blockIdx.x;
    const int t = threadIdx.x;
    const float* base = adj + (size_t)i * EE;
    float t0 = 0.f, t1 = 0.f;
#pragma unroll
    for (int r = 0; r < RRR; ++r) {
        t0 += base[(size_t)r * EE * EE + t];
        t1 += base[(size_t)r * EE * EE + t + 256];
    }
    const float e0 = __expf(t0);
    const float e1 = __expf(t1);
    __shared__ float red[256];
    red[t] = e0 + e1;
    __syncthreads();
    for (int off = 128; off > 0; off >>= 1) {
        if (t < off) red[t] += red[t + off];
        __syncthreads();
    }
    const float inv = 1.0f / red[0];
    s[(size_t)i * EE + t]       = e0 * inv;
    s[(size_t)i * EE + t + 256] = e1 * inv;
}

// --- Kernel B: Z[j,f] = sum_i exp(lrelu(s[i,j]*h[i,f]*h[j,f]));
//               g[j,f] = h[j,f] / Z[j,f] -----------------------------------
__global__ __launch_bounds__(256) void kB(const float* __restrict__ h,
                                          const float* __restrict__ s,
                                          float* __restrict__ g) {
    const int j = blockIdx.x;
    const int f = threadIdx.x;
    __shared__ float scol[EE];
    // stage the j-th column of s (strided reads, L2-resident, small)
    scol[f]       = s[(size_t)f * EE + j];
    scol[f + 256] = s[(size_t)(f + 256) * EE + j];
    __syncthreads();
    const float hj = h[(size_t)j * FF + f];
    float Z = 0.f;
#pragma unroll 8
    for (int i = 0; i < EE; ++i) {
        const float x = scol[i] * hj * h[(size_t)i * FF + f];
        Z += __expf(fmaxf(x, 0.2f * x));   // lrelu(x) = max(x, 0.2x)
    }
    g[(size_t)j * FF + f] = hj / Z;
}

// --- Kernel C: h_prime[i,f] = sum_j g[j,f]*exp(lrelu(s[i,j]*h[i,f]*h[j,f]));
//               out = elu(h_prime); also fill alpha = 1/E ------------------
__global__ __launch_bounds__(256) void kC(const float* __restrict__ h,
                                          const float* __restrict__ s,
                                          const float* __restrict__ g,
                                          float* __restrict__ out) {
    const int i = blockIdx.x;
    const int f = threadIdx.x;
    __shared__ float srow[EE];
    srow[f]       = s[(size_t)i * EE + f];
    srow[f + 256] = s[(size_t)i * EE + f + 256];
    __syncthreads();
    const float hif = h[(size_t)i * FF + f];
    float acc = 0.f;
#pragma unroll 8
    for (int j = 0; j < EE; ++j) {
        const float x = srow[j] * hif * h[(size_t)j * FF + f];
        acc += g[(size_t)j * FF + f] * __expf(fmaxf(x, 0.2f * x));
    }
    out[(size_t)i * FF + f] = (acc > 0.f) ? acc : (__expf(acc) - 1.0f);
    if (i == 0) {
        // alpha = softmax of a constant vector = 1/E, exactly uniform.
        out[EE * FF + f]       = 1.0f / EE;
        out[EE * FF + 256 + f] = 1.0f / EE;
    }
}

extern "C" void kernel_launch(void* const* d_in, const int* in_sizes, int n_in,
                              void* d_out, int out_size, void* d_ws, size_t ws_size,
                              hipStream_t stream) {
    const float* h   = (const float*)d_in[0];  // [E,F]
    const float* adj = (const float*)d_in[1];  // [R,E,E]
    // lin_w (d_in[2]) and lin_b (d_in[3]) are mathematically dead (see alpha note).

    float* s = (float*)d_ws;             // E*E floats = 1 MB
    float* g = s + (size_t)EE * EE;      // E*F floats = 512 KB  (total 1.5 MB <= ws_size)
    float* out = (float*)d_out;

    kA<<<EE, 256, 0, stream>>>(adj, s);
    kB<<<EE, 256, 0, stream>>>(h, s, g);
    kC<<<EE, 256, 0, stream>>>(h, s, g, out);
}

// Round 2
// 49.633 us; speedup vs baseline: 1.0829x; 1.0829x over previous
//
#include <hip/hip_runtime.h>

// CenterNeighAtt on MI355X. E=512, F=256, R=4.
//
// Exact math simplifications:
//  * alpha = softmax_j(sum_i scores[i,j]) is uniform 1/E: sum_i attention[i,j,f]==1
//    (softmax over i), so column sums of scores are constant in j. lin_w/lin_b dead.
//  * No max-subtraction needed: logits bounded (~20), exp stays far below f32
//    overflow; plain exp/sum is mathematically identical. (Validated R1: absmax 2.4e-4.)
//
// Structure (split-K for occupancy + register tiling for L2 traffic):
//  kA : s[i,j] = softmax_j(sum_r adj[r,i,j])
//  kB : Zp[c][j][f] = sum_{i in chunk c} exp2(lrelu(s[i,j]*h[i,f]*h[j,f])*log2e)
//  kB2: g[j,f] = h[j,f] / sum_c Zp[c][j][f]
//  kC : Hp[c][i][f] = sum_{j in chunk c} g[j,f]*exp2(lrelu(s[i,j]*h[i,f]*h[j,f])*log2e)
//  kC2: out = elu(sum_c Hp); alpha = 1/E

#define EE 512
#define FF 256
#define RRR 4
#define LOG2E 1.44269504088896340736f
#define TT 8     // row tile per block (kB: j's, kC: i's)
#define NCH 8    // reduction-axis chunks
#define CLEN 64  // 512 / NCH

// --- kA: s[i,:] = softmax(sum_r adj[r,i,:]) --------------------------------
__global__ __launch_bounds__(256) void kA(const float* __restrict__ adj,
                                          float* __restrict__ s) {
    const int i = blockIdx.x;
    const int t = threadIdx.x;
    const float* base = adj + (size_t)i * EE;
    float t0 = 0.f, t1 = 0.f;
#pragma unroll
    for (int r = 0; r < RRR; ++r) {
        t0 += base[(size_t)r * EE * EE + t];
        t1 += base[(size_t)r * EE * EE + t + 256];
    }
    const float e0 = __expf(t0);
    const float e1 = __expf(t1);
    __shared__ float red[256];
    red[t] = e0 + e1;
    __syncthreads();
    for (int off = 128; off > 0; off >>= 1) {
        if (t < off) red[t] += red[t + off];
        __syncthreads();
    }
    const float inv = 1.0f / red[0];
    s[(size_t)i * EE + t]       = e0 * inv;
    s[(size_t)i * EE + t + 256] = e1 * inv;
}

// --- kB: partial denominators over i-chunks --------------------------------
__global__ __launch_bounds__(256) void kB(const float* __restrict__ h,
                                          const float* __restrict__ s,
                                          float* __restrict__ Zp) {
    const int j0 = blockIdx.x * TT;   // 8 j's per block
    const int c  = blockIdx.y;        // i-chunk
    const int i0 = c * CLEN;
    const int f  = threadIdx.x;
    __shared__ float sl[CLEN][TT];    // s[i0+ii][j0+tj]
    for (int idx = threadIdx.x; idx < CLEN * TT; idx += 256) {
        const int ii = idx >> 3, tj = idx & 7;
        sl[ii][tj] = s[(size_t)(i0 + ii) * EE + j0 + tj];
    }
    __syncthreads();
    float hj[TT], Z[TT];
#pragma unroll
    for (int tj = 0; tj < TT; ++tj) {
        hj[tj] = h[(size_t)(j0 + tj) * FF + f] * LOG2E;  // fold log2e
        Z[tj] = 0.f;
    }
    for (int ii = 0; ii < CLEN; ++ii) {
        const float hif = h[(size_t)(i0 + ii) * FF + f];
#pragma unroll
        for (int tj = 0; tj < TT; ++tj) {
            const float y = sl[ii][tj] * hif * hj[tj];
            const float z = fmaxf(y, 0.2f * y);          // lrelu (scaled by log2e)
            Z[tj] += __builtin_amdgcn_exp2f(z);
        }
    }
#pragma unroll
    for (int tj = 0; tj < TT; ++tj)
        Zp[((size_t)c * EE + j0 + tj) * FF + f] = Z[tj];
}

// --- kB2: g[j,f] = h[j,f] / sum_c Zp ---------------------------------------
__global__ __launch_bounds__(256) void kB2(const float* __restrict__ h,
                                           const float* __restrict__ Zp,
                                           float* __restrict__ g) {
    const int j = blockIdx.x, f = threadIdx.x;
    float zs = 0.f;
#pragma unroll
    for (int c = 0; c < NCH; ++c) zs += Zp[((size_t)c * EE + j) * FF + f];
    g[(size_t)j * FF + f] = h[(size_t)j * FF + f] / zs;
}

// --- kC: partial numerators over j-chunks ----------------------------------
__global__ __launch_bounds__(256) void kC(const float* __restrict__ h,
                                          const float* __restrict__ s,
                                          const float* __restrict__ g,
                                          float* __restrict__ Hp) {
    const int i0 = blockIdx.x * TT;   // 8 i's per block
    const int c  = blockIdx.y;        // j-chunk
    const int j0 = c * CLEN;
    const int f  = threadIdx.x;
    __shared__ float sl[CLEN][TT];    // s[i0+ti][j0+jj]
    for (int idx = threadIdx.x; idx < CLEN * TT; idx += 256) {
        const int jj = idx >> 3, ti = idx & 7;
        sl[jj][ti] = s[(size_t)(i0 + ti) * EE + j0 + jj];
    }
    __syncthreads();
    float hl[TT], acc[TT];
#pragma unroll
    for (int ti = 0; ti < TT; ++ti) {
        hl[ti] = h[(size_t)(i0 + ti) * FF + f] * LOG2E;  // fold log2e
        acc[ti] = 0.f;
    }
    for (int jj = 0; jj < CLEN; ++jj) {
        const float hjf = h[(size_t)(j0 + jj) * FF + f];
        const float gj  = g[(size_t)(j0 + jj) * FF + f];
#pragma unroll
        for (int ti = 0; ti < TT; ++ti) {
            const float y = sl[jj][ti] * hl[ti] * hjf;
            const float z = fmaxf(y, 0.2f * y);
            acc[ti] = fmaf(__builtin_amdgcn_exp2f(z), gj, acc[ti]);
        }
    }
#pragma unroll
    for (int ti = 0; ti < TT; ++ti)
        Hp[((size_t)c * EE + i0 + ti) * FF + f] = acc[ti];
}

// --- kC2: out = elu(sum_c Hp); alpha = 1/E ---------------------------------
__global__ __launch_bounds__(256) void kC2(const float* __restrict__ Hp,
                                           float* __restrict__ out) {
    const int i = blockIdx.x, f = threadIdx.x;
    float a = 0.f;
#pragma unroll
    for (int c = 0; c < NCH; ++c) a += Hp[((size_t)c * EE + i) * FF + f];
    out[(size_t)i * FF + f] = (a > 0.f) ? a : (__expf(a) - 1.0f);
    if (i == 0) {
        out[EE * FF + f]       = 1.0f / EE;   // alpha: softmax of constant = uniform
        out[EE * FF + 256 + f] = 1.0f / EE;
    }
}

extern "C" void kernel_launch(void* const* d_in, const int* in_sizes, int n_in,
                              void* d_out, int out_size, void* d_ws, size_t ws_size,
                              hipStream_t stream) {
    const float* h   = (const float*)d_in[0];  // [E,F]
    const float* adj = (const float*)d_in[1];  // [R,E,E]
    // lin_w / lin_b mathematically dead (alpha uniform).

    float* s  = (float*)d_ws;                       // 1 MB
    float* g  = s  + (size_t)EE * EE;               // 512 KB
    float* Zp = g  + (size_t)EE * FF;               // 4 MB
    float* Hp = Zp + (size_t)NCH * EE * FF;         // 4 MB   (total ~9.5 MB)
    float* out = (float*)d_out;

    kA <<<EE, 256, 0, stream>>>(adj, s);
    kB <<<dim3(EE / TT, NCH), 256, 0, stream>>>(h, s, Zp);
    kB2<<<EE, 256, 0, stream>>>(h, Zp, g);
    kC <<<dim3(EE / TT, NCH), 256, 0, stream>>>(h, s, g, Hp);
    kC2<<<EE, 256, 0, stream>>>(Hp, out);
}